// Round 4
// baseline (59.509 us; speedup 1.0000x reference)
//
#include <hip/hip_runtime.h>

#define IMG 512
#define TW 64
#define TH 16
#define RROWS 26      // TH + 2*5
#define RST 80        // RAW stride; RAW col j <-> gx = tx0 - 8 + j
#define UST 144       // UBi stride (72 interleaved (min,max) pairs)
#define H2  128       // SH2 stride for interleaved h11 (64 pairs)

__device__ __forceinline__ float nan0(float v) { return v == v ? v : 0.0f; }
__device__ __forceinline__ float min3f(float a, float b, float c){ return fminf(fminf(a,b),c); }
__device__ __forceinline__ float max3f(float a, float b, float c){ return fmaxf(fmaxf(a,b),c); }

__global__ __launch_bounds__(256, 4)
void simplenet_fused(const float* __restrict__ X,
                     const float* __restrict__ w0, const float* __restrict__ b0,
                     const float* __restrict__ w1, const float* __restrict__ w2,
                     const float* __restrict__ w3, const float* __restrict__ w4,
                     const float* __restrict__ w5, const float* __restrict__ w6,
                     float* __restrict__ out)
{
    __shared__ float RAW[RROWS][RST];     //  8320 B raw tile (NaN = OOB)
    __shared__ float UBi[RROWS][UST];     // 14976 B (min3,max3) pairs, idx i <-> RAW col i+4
    __shared__ float SH2[RROWS * H2];     // 13312 B gaussH rows (stride 64) then h11 pairs (stride 128)

    const int tid = threadIdx.x;
    const int xo  = tid & 63;
    const int ty  = tid >> 6;
    const int y0  = ty * 4;               // 4 consecutive output rows / thread
    const int bx = blockIdx.x, by = blockIdx.y, bz = blockIdx.z;
    const int tx0 = bx * TW, ty0 = by * TH;
    const bool xe = (bx == 0) || (bx == IMG/TW - 1);
    const bool ye = (by == 0) || (by == IMG/TH - 1);
    const float* Xb = X + (size_t)bz * (IMG*IMG);

    const float W0c0 = w0[0], W0c1 = w0[1];
    const float B0   = b0[0], B1   = b0[1];
    const float W1c0 = w1[0], W1c1 = w1[1];
    const float W2c0 = w2[0], W2c1 = w2[1];
    const float W3c0 = w3[0], W3c1 = w3[1];
    const float W4c0 = w4[0], W4c1 = w4[1];
    const float W5c0 = w5[0], W5c1 = w5[1];
    const float W6c0 = w6[0], W6c1 = w6[1];

    // ---- P0: stage RAW (NaN sentinel OOB) ----
    if (!xe) {
        for (int t = tid; t < RROWS*20; t += 256) {
            const int r = t / 20, c4 = t - r*20;
            const int gy = ty0 - 5 + r;
            float4 v;
            if (!ye || (unsigned)gy < IMG)
                v = *(const float4*)(Xb + gy*IMG + (tx0 - 8 + 4*c4));
            else {
                const float qn = __builtin_nanf("");
                v = make_float4(qn, qn, qn, qn);
            }
            *(float4*)(&RAW[r][4*c4]) = v;
        }
    } else {
        for (int t = tid; t < RROWS*RST; t += 256) {
            const int r = t / RST, c = t - r*RST;
            const int gy = ty0 - 5 + r, gx = tx0 - 8 + c;
            RAW[r][c] = ((unsigned)gy < IMG && (unsigned)gx < IMG)
                        ? Xb[gy*IMG + gx] : __builtin_nanf("");
        }
    }
    __syncthreads();

    const float G0 = 0.10628875f, G1 = 0.14032194f, G2 = 0.16577342f, G3 = 0.17523179f;

    // ---- P1: gaussH -> SH2 rows 0..21 (stride 64); GH row gi = RAW row gi+2 ----
    for (int t = tid; t < 22*16; t += 256) {
        const int r  = (t >> 4) + 2;
        const int cg = (t & 15) * 4;
        const float4 A = *(const float4*)&RAW[r][cg+4];
        const float4 Bq = *(const float4*)&RAW[r][cg+8];
        const float4 Cq = *(const float4*)&RAW[r][cg+12];
        float rr[12] = {A.x,A.y,A.z,A.w, Bq.x,Bq.y,Bq.z,Bq.w, Cq.x,Cq.y,Cq.z,Cq.w};
        float rz[12];
        if (xe) {
#pragma unroll
            for (int i = 0; i < 12; ++i) rz[i] = nan0(rr[i]);
        } else {
#pragma unroll
            for (int i = 0; i < 12; ++i) rz[i] = rr[i];
        }
        float h[4];
#pragma unroll
        for (int k = 0; k < 4; ++k)
            h[k] = G0*(rz[k+1]+rz[k+7]) + G1*(rz[k+2]+rz[k+6]) + G2*(rz[k+3]+rz[k+5]) + G3*rr[k+4];
        *(float4*)&SH2[(r-2)*64 + cg] = make_float4(h[0],h[1],h[2],h[3]);
    }

    // ---- P2: (min3,max3) pairs; UBi idx i <-> RAW col i+4, i in 0..71 ----
    for (int t = tid; t < 26*18; t += 256) {
        const int r  = t / 18;
        const int g  = t - r*18;
        const int i4 = 4*g;
        const float2 a = *(const float2*)&RAW[r][i4+2];   // cols i4+2,3  (v0,v1)
        const float4 bq = *(const float4*)&RAW[r][i4+4];  // cols i4+4..7 (v2..v5)
        const float  v6 = RAW[r][i4+8];
        const float v1=a.y, v2=bq.x, v3=bq.y, v4=bq.z, v5=bq.w;
        const float mn0=min3f(v1,v2,v3), mn1=min3f(v2,v3,v4), mn2=min3f(v3,v4,v5), mn3=min3f(v4,v5,v6);
        const float mx0=max3f(v1,v2,v3), mx1=max3f(v2,v3,v4), mx2=max3f(v3,v4,v5), mx3=max3f(v4,v5,v6);
        *(float4*)&UBi[r][2*i4]     = make_float4(mn0,mx0,mn1,mx1);
        *(float4*)&UBi[r][2*i4 + 4] = make_float4(mn2,mx2,mn3,mx3);
    }
    __syncthreads();

    float a0[4], a1[4];

    // ---- P3: gaussV (consume GH rows before SH2 is re-used) ----
    {
        float wv[10];
#pragma unroll
        for (int i = 0; i < 10; ++i) wv[i] = SH2[(y0+i)*64 + xo];
        if (ye) {
#pragma unroll
            for (int i = 0; i < 10; ++i) wv[i] = nan0(wv[i]);
        }
#pragma unroll
        for (int p = 0; p < 4; ++p) {
            const float s = G0*(wv[p]+wv[p+6]) + G1*(wv[p+1]+wv[p+5])
                          + G2*(wv[p+2]+wv[p+4]) + G3*wv[p+3];
            a0[p] = B0 + W2c0*s;
            a1[p] = B1 + W2c1*s;
        }
    }
    __syncthreads();   // GH fully consumed; SH2 reusable

    // ---- P4: h11 pairs via composition: h11[c] = m(U[c],U[c+3],U[c+6],U[c+8]) ----
    for (int t = tid; t < 26*16; t += 256) {
        const int r  = t >> 4;
        const int c4 = (t & 15) * 4;
        const int ub = 2*c4;
        const float4 q0 = *(const float4*)&UBi[r][ub];
        const float4 q1 = *(const float4*)&UBi[r][ub+4];
        const float4 q2 = *(const float4*)&UBi[r][ub+8];
        const float4 q3 = *(const float4*)&UBi[r][ub+12];
        const float4 q4 = *(const float4*)&UBi[r][ub+16];
        const float4 q5 = *(const float4*)&UBi[r][ub+20];
        const float un[12] = {q0.x,q0.z,q1.x,q1.z,q2.x,q2.z,q3.x,q3.z,q4.x,q4.z,q5.x,q5.z};
        const float ux[12] = {q0.y,q0.w,q1.y,q1.w,q2.y,q2.w,q3.y,q3.w,q4.y,q4.w,q5.y,q5.w};
        float mn[4], mx[4];
#pragma unroll
        for (int k = 0; k < 4; ++k) {
            mn[k] = fminf(fminf(un[k],un[k+3]), fminf(un[k+6],un[k+8]));
            mx[k] = fmaxf(fmaxf(ux[k],ux[k+3]), fmaxf(ux[k+6],ux[k+8]));
        }
        *(float4*)&SH2[r*H2 + 2*c4]     = make_float4(mn[0],mx[0],mn[1],mx[1]);
        *(float4*)&SH2[r*H2 + 2*c4 + 4] = make_float4(mn[2],mx[2],mn[3],mx[3]);
    }
    __syncthreads();

    // ---- P5a: identity + 3x3 cross ----
    {
        const int xc = xo + 8;
        float c0 = RAW[y0+4][xc], c1 = RAW[y0+5][xc], c2 = RAW[y0+6][xc],
              c3 = RAW[y0+7][xc], c4v = RAW[y0+8][xc], c5 = RAW[y0+9][xc];
        float l0 = RAW[y0+5][xc-1], l1 = RAW[y0+6][xc-1], l2 = RAW[y0+7][xc-1], l3 = RAW[y0+8][xc-1];
        float r0 = RAW[y0+5][xc+1], r1 = RAW[y0+6][xc+1], r2 = RAW[y0+7][xc+1], r3 = RAW[y0+8][xc+1];
        if (ye) { c0 = nan0(c0); c5 = nan0(c5); }
        if (xe) { l0=nan0(l0); l1=nan0(l1); l2=nan0(l2); l3=nan0(l3);
                  r0=nan0(r0); r1=nan0(r1); r2=nan0(r2); r3=nan0(r3); }
        const float cc[6] = {c0,c1,c2,c3,c4v,c5};
        const float ll[4] = {l0,l1,l2,l3};
        const float rr[4] = {r0,r1,r2,r3};
#pragma unroll
        for (int p = 0; p < 4; ++p) {
            const float cr = 0.25f * (cc[p] + cc[p+2] + ll[p] + rr[p]);
            a0[p] += W0c0*cc[p+1] + W1c0*cr;
            a1[p] += W0c1*cc[p+1] + W1c1*cr;
        }
    }

    // ---- P5b: pool3 vertical from UBi pairs (center idx xo+4) ----
    {
        float2 u[6];
#pragma unroll
        for (int i = 0; i < 6; ++i) u[i] = *(const float2*)&UBi[y0+4+i][2*(xo+4)];
#pragma unroll
        for (int p = 0; p < 4; ++p) {
            const float mn = min3f(u[p].x, u[p+1].x, u[p+2].x);
            const float mx = max3f(u[p].y, u[p+1].y, u[p+2].y);
            a0[p] += W3c0*mn + W5c0*mx;
            a1[p] += W3c1*mn + W5c1*mx;
        }
    }

    // ---- P5c: v11 van Herk over 14 interleaved h11 rows ----
    {
        float2 h[14];
#pragma unroll
        for (int i = 0; i < 14; ++i) h[i] = *(const float2*)&SH2[(y0+i)*H2 + 2*xo];
        float an = h[10].x, ax = h[10].y;
#pragma unroll
        for (int i = 9; i >= 4; --i) { an = fminf(an, h[i].x); ax = fmaxf(ax, h[i].y); }
        const float Sn3 = fminf(an, h[3].x),  Sx3 = fmaxf(ax, h[3].y);
        const float Sn2 = fminf(Sn3, h[2].x), Sx2 = fmaxf(Sx3, h[2].y);
        const float Sn1 = fminf(Sn2, h[1].x), Sx1 = fmaxf(Sx2, h[1].y);
        const float Sn0 = fminf(Sn1, h[0].x), Sx0 = fmaxf(Sx1, h[0].y);
        const float pn1 = h[11].x,            px1 = h[11].y;
        const float pn2 = fminf(pn1, h[12].x), px2 = fmaxf(px1, h[12].y);
        const float pn3 = fminf(pn2, h[13].x), px3 = fmaxf(px2, h[13].y);
        const float on[4] = {Sn0, fminf(Sn1,pn1), fminf(Sn2,pn2), fminf(Sn3,pn3)};
        const float ox[4] = {Sx0, fmaxf(Sx1,px1), fmaxf(Sx2,px2), fmaxf(Sx3,px3)};
#pragma unroll
        for (int p = 0; p < 4; ++p) {
            a0[p] += W4c0*on[p] + W6c0*ox[p];
            a1[p] += W4c1*on[p] + W6c1*ox[p];
        }
    }

    float* o0p = out + ((size_t)bz*2 + 0)*(IMG*IMG) + (size_t)(ty0+y0)*IMG + tx0 + xo;
    float* o1p = o0p + (IMG*IMG);
#pragma unroll
    for (int p = 0; p < 4; ++p) {
        o0p[(size_t)p*IMG] = a0[p];
        o1p[(size_t)p*IMG] = a1[p];
    }
}

extern "C" void kernel_launch(void* const* d_in, const int* in_sizes, int n_in,
                              void* d_out, int out_size, void* d_ws, size_t ws_size,
                              hipStream_t stream) {
    const float* X  = (const float*)d_in[0];
    const float* w0 = (const float*)d_in[1];
    const float* b0 = (const float*)d_in[2];
    const float* w1 = (const float*)d_in[3];
    const float* w2 = (const float*)d_in[4];
    const float* w3 = (const float*)d_in[5];
    const float* w4 = (const float*)d_in[6];
    const float* w5 = (const float*)d_in[7];
    const float* w6 = (const float*)d_in[8];
    float* out = (float*)d_out;

    dim3 grid(IMG / TW, IMG / TH, 32);
    simplenet_fused<<<grid, 256, 0, stream>>>(X, w0, b0, w1, w2, w3, w4, w5, w6, out);
}

// Round 5
// 49.904 us; speedup vs baseline: 1.1925x; 1.1925x over previous
//
#include <hip/hip_runtime.h>

#define IMG 512
#define TW 64
#define TH 16
#define RST 80      // RAW stride (floats); col j <-> gx = tx0-8+j
#define GST 64      // GH stride
#define PST 132     // HP stride; (min,max) pair for col c at offset 2c

__device__ __forceinline__ float nan0(float v){ return v==v ? v : 0.0f; }
__device__ __forceinline__ float min3f(float a,float b,float c){ return fminf(fminf(a,b),c); }
__device__ __forceinline__ float max3f(float a,float b,float c){ return fmaxf(fmaxf(a,b),c); }

__global__ __launch_bounds__(256,5)
void simplenet_fused(const float* __restrict__ X,
                     const float* __restrict__ w0, const float* __restrict__ b0,
                     const float* __restrict__ w1, const float* __restrict__ w2,
                     const float* __restrict__ w3, const float* __restrict__ w4,
                     const float* __restrict__ w5, const float* __restrict__ w6,
                     float* __restrict__ out)
{
    __shared__ float RAW[26*RST];   //  8320 B raw tile, NaN = OOB sentinel
    __shared__ float GH[22*GST];    //  5632 B gaussH rows (GH row r = RAW row r+2)
    __shared__ float HP[26*PST];    // 13728 B interleaved (h11min,h11max) pairs

    const int tid = threadIdx.x;
    const int xo = tid & 63, ty = tid >> 6, y0 = ty*4;
    const int bx = blockIdx.x, by = blockIdx.y, bz = blockIdx.z;
    const int tx0 = bx*TW, ty0 = by*TH;
    const bool xe = (bx==0)||(bx==IMG/TW-1);
    const bool ye = (by==0)||(by==IMG/TH-1);
    const float* Xb = X + (size_t)bz*(IMG*IMG);

    const float W0c0=w0[0], W0c1=w0[1], B0=b0[0], B1=b0[1];
    const float W1c0=w1[0], W1c1=w1[1], W2c0=w2[0], W2c1=w2[1];
    const float W3c0=w3[0], W3c1=w3[1], W4c0=w4[0], W4c1=w4[1];
    const float W5c0=w5[0], W5c1=w5[1], W6c0=w6[0], W6c1=w6[1];

    // ---- stage RAW (NaN sentinel for OOB) ----
    if (!xe) {
        for (int t=tid; t<520; t+=256) {               // 26 rows x 20 float4
            const int r = t/20, c4 = t - r*20;
            const int gy = ty0 - 5 + r;
            float4 v;
            if (!ye || (unsigned)gy < IMG)
                v = *(const float4*)(Xb + gy*IMG + (tx0-8+4*c4));
            else { const float qn=__builtin_nanf(""); v = make_float4(qn,qn,qn,qn); }
            *(float4*)&RAW[r*RST + 4*c4] = v;
        }
    } else {
        for (int t=tid; t<26*RST; t+=256) {
            const int r = t/RST, c = t - r*RST;
            const int gy = ty0-5+r, gx = tx0-8+c;
            RAW[r*RST+c] = ((unsigned)gy<IMG && (unsigned)gx<IMG)
                           ? Xb[gy*IMG+gx] : __builtin_nanf("");
        }
    }
    __syncthreads();

    const float G0=0.10628875f, G1=0.14032194f, G2=0.16577342f, G3=0.17523179f;

    // ---- gaussH producer: 4 outputs/task, 3 b128 reads + 1 b128 write ----
    auto gh_task = [&](int r, int g) {
        const int base = (r+2)*RST + 4*g;
        const float4 A  = *(const float4*)&RAW[base+4];
        const float4 Bq = *(const float4*)&RAW[base+8];
        const float4 Cq = *(const float4*)&RAW[base+12];
        float x[12] = {A.x,A.y,A.z,A.w, Bq.x,Bq.y,Bq.z,Bq.w, Cq.x,Cq.y,Cq.z,Cq.w};
        if (xe) {
#pragma unroll
            for (int i=0;i<12;++i) x[i]=nan0(x[i]);   // centers x[4..7] are in-tile, nan0 is identity there
        }
        float h[4];
#pragma unroll
        for (int k=0;k<4;++k)
            h[k] = G0*(x[k+1]+x[k+7]) + G1*(x[k+2]+x[k+6]) + G2*(x[k+3]+x[k+5]) + G3*x[k+4];
        *(float4*)&GH[r*GST+4*g] = make_float4(h[0],h[1],h[2],h[3]);
    };
    gh_task(tid>>4, tid&15);                 // rows 0..15
    if (tid < 96) gh_task(16+(tid>>4), tid&15);  // rows 16..21

    // ---- pool producer: h11 min&max for 4 cols, 5 b128 reads + 2 b128 pair-writes ----
    auto pl_task = [&](int r, int g) {
        const int base = r*RST + 4*g;
        const float4 q0=*(const float4*)&RAW[base];
        const float4 q1=*(const float4*)&RAW[base+4];
        const float4 q2=*(const float4*)&RAW[base+8];
        const float4 q3=*(const float4*)&RAW[base+12];
        const float4 q4=*(const float4*)&RAW[base+16];
        const float x[20] = {q0.x,q0.y,q0.z,q0.w, q1.x,q1.y,q1.z,q1.w,
                             q2.x,q2.y,q2.z,q2.w, q3.x,q3.y,q3.z,q3.w,
                             q4.x,q4.y,q4.z,q4.w};
        float mn[12], mx[12];
#pragma unroll
        for (int i=0;i<12;++i) {              // running 3-min/max centered at x[i+4]
            mn[i] = min3f(x[i+3],x[i+4],x[i+5]);
            mx[i] = max3f(x[i+3],x[i+4],x[i+5]);
        }
        float an[4], ax[4];
#pragma unroll
        for (int k=0;k<4;++k) {               // 11-window = m3 at offsets 0,3,6,8
            an[k] = fminf(fminf(mn[k],mn[k+3]), fminf(mn[k+6],mn[k+8]));
            ax[k] = fmaxf(fmaxf(mx[k],mx[k+3]), fmaxf(mx[k+6],mx[k+8]));
        }
        *(float4*)&HP[r*PST+8*g]   = make_float4(an[0],ax[0],an[1],ax[1]);
        *(float4*)&HP[r*PST+8*g+4] = make_float4(an[2],ax[2],an[3],ax[3]);
    };
    pl_task(tid>>4, tid&15);                  // rows 0..15
    if (tid < 160) pl_task(16+(tid>>4), tid&15);  // rows 16..25

    float a0[4], a1[4];

    // ---- identity + 3x3 cross (reads RAW, no dependency on producers) ----
    {
        const int xc = xo+8;
        float c0=RAW[(y0+4)*RST+xc], c1=RAW[(y0+5)*RST+xc], c2=RAW[(y0+6)*RST+xc],
              c3=RAW[(y0+7)*RST+xc], c4v=RAW[(y0+8)*RST+xc], c5=RAW[(y0+9)*RST+xc];
        float l0=RAW[(y0+5)*RST+xc-1], l1=RAW[(y0+6)*RST+xc-1],
              l2=RAW[(y0+7)*RST+xc-1], l3=RAW[(y0+8)*RST+xc-1];
        float r0=RAW[(y0+5)*RST+xc+1], r1=RAW[(y0+6)*RST+xc+1],
              r2=RAW[(y0+7)*RST+xc+1], r3=RAW[(y0+8)*RST+xc+1];
        if (ye) { c0=nan0(c0); c5=nan0(c5); }
        if (xe) { l0=nan0(l0); l1=nan0(l1); l2=nan0(l2); l3=nan0(l3);
                  r0=nan0(r0); r1=nan0(r1); r2=nan0(r2); r3=nan0(r3); }
        const float cc[6]={c0,c1,c2,c3,c4v,c5};
        const float ll[4]={l0,l1,l2,l3};
        const float rr[4]={r0,r1,r2,r3};
#pragma unroll
        for (int p=0;p<4;++p) {
            const float cr = 0.25f*(cc[p]+cc[p+2]+ll[p]+rr[p]);
            a0[p] = B0 + W0c0*cc[p+1] + W1c0*cr;
            a1[p] = B1 + W0c1*cc[p+1] + W1c1*cr;
        }
    }

    // ---- pool3 3x3 min/max direct from RAW (18 shared b32 reads) ----
    {
        float hm[6], hx[6];
#pragma unroll
        for (int i=0;i<6;++i) {
            const int rb=(y0+4+i)*RST+xo+7;
            const float v0=RAW[rb], v1=RAW[rb+1], v2=RAW[rb+2];
            hm[i]=min3f(v0,v1,v2);
            hx[i]=max3f(v0,v1,v2);
        }
#pragma unroll
        for (int p=0;p<4;++p) {
            const float mn=min3f(hm[p],hm[p+1],hm[p+2]);
            const float mx=max3f(hx[p],hx[p+1],hx[p+2]);
            a0[p]+=W3c0*mn+W5c0*mx;
            a1[p]+=W3c1*mn+W5c1*mx;
        }
    }
    __syncthreads();

    // ---- gaussV from GH (column b32 reads, conflict-free) ----
    {
        float wv[10];
#pragma unroll
        for (int i=0;i<10;++i) wv[i]=GH[(y0+i)*GST+xo];
        if (ye) {
#pragma unroll
            for (int i=0;i<10;++i) wv[i]=nan0(wv[i]);
        }
#pragma unroll
        for (int p=0;p<4;++p) {
            const float s = G0*(wv[p]+wv[p+6]) + G1*(wv[p+1]+wv[p+5])
                          + G2*(wv[p+2]+wv[p+4]) + G3*wv[p+3];
            a0[p]+=W2c0*s; a1[p]+=W2c1*s;
        }
    }

    // ---- v11 van Herk over 14 (min,max) pair rows (b64 reads, 8B lane stride = free) ----
    {
        float2 h[14];
#pragma unroll
        for (int i=0;i<14;++i) h[i] = *(const float2*)&HP[(y0+i)*PST + 2*xo];
        float an = h[10].x, ax = h[10].y;
#pragma unroll
        for (int i=9;i>=4;--i) { an=fminf(an,h[i].x); ax=fmaxf(ax,h[i].y); }
        const float Sn3=fminf(an,h[3].x),  Sx3=fmaxf(ax,h[3].y);
        const float Sn2=fminf(Sn3,h[2].x), Sx2=fmaxf(Sx3,h[2].y);
        const float Sn1=fminf(Sn2,h[1].x), Sx1=fmaxf(Sx2,h[1].y);
        const float Sn0=fminf(Sn1,h[0].x), Sx0=fmaxf(Sx1,h[0].y);
        const float pn1=h[11].x,            px1=h[11].y;
        const float pn2=fminf(pn1,h[12].x), px2=fmaxf(px1,h[12].y);
        const float pn3=fminf(pn2,h[13].x), px3=fmaxf(px2,h[13].y);
        const float on[4]={Sn0, fminf(Sn1,pn1), fminf(Sn2,pn2), fminf(Sn3,pn3)};
        const float ox[4]={Sx0, fmaxf(Sx1,px1), fmaxf(Sx2,px2), fmaxf(Sx3,px3)};
#pragma unroll
        for (int p=0;p<4;++p) {
            a0[p]+=W4c0*on[p]+W6c0*ox[p];
            a1[p]+=W4c1*on[p]+W6c1*ox[p];
        }
    }

    float* o0p = out + ((size_t)bz*2 + 0)*(IMG*IMG) + (size_t)(ty0+y0)*IMG + tx0 + xo;
    float* o1p = o0p + (IMG*IMG);
#pragma unroll
    for (int p=0;p<4;++p) {
        o0p[(size_t)p*IMG] = a0[p];
        o1p[(size_t)p*IMG] = a1[p];
    }
}

extern "C" void kernel_launch(void* const* d_in, const int* in_sizes, int n_in,
                              void* d_out, int out_size, void* d_ws, size_t ws_size,
                              hipStream_t stream) {
    const float* X  = (const float*)d_in[0];
    const float* w0 = (const float*)d_in[1];
    const float* b0 = (const float*)d_in[2];
    const float* w1 = (const float*)d_in[3];
    const float* w2 = (const float*)d_in[4];
    const float* w3 = (const float*)d_in[5];
    const float* w4 = (const float*)d_in[6];
    const float* w5 = (const float*)d_in[7];
    const float* w6 = (const float*)d_in[8];
    float* out = (float*)d_out;

    dim3 grid(IMG/TW, IMG/TH, 32);
    simplenet_fused<<<grid, 256, 0, stream>>>(X, w0, b0, w1, w2, w3, w4, w5, w6, out);
}

// Round 6
// 49.575 us; speedup vs baseline: 1.2004x; 1.0066x over previous
//
#include <hip/hip_runtime.h>

#define IMG 512
#define TW 64
#define TH 16
#define RST 80      // RAW stride (floats); col j <-> gx = tx0-8+j
#define GST 64      // GH stride
#define HST 64      // HN/HX stride

__device__ __forceinline__ float nan0(float v){ return v==v ? v : 0.0f; }
__device__ __forceinline__ float min3f(float a,float b,float c){ return fminf(fminf(a,b),c); }
__device__ __forceinline__ float max3f(float a,float b,float c){ return fmaxf(fmaxf(a,b),c); }

__global__ __launch_bounds__(256,6)
void simplenet_fused(const float* __restrict__ X,
                     const float* __restrict__ w0, const float* __restrict__ b0,
                     const float* __restrict__ w1, const float* __restrict__ w2,
                     const float* __restrict__ w3, const float* __restrict__ w4,
                     const float* __restrict__ w5, const float* __restrict__ w6,
                     float* __restrict__ out)
{
    __shared__ float RAW[26*RST];   // 8320 B raw tile, NaN = OOB sentinel
    __shared__ float GH[22*GST];    // 5632 B gaussH rows (GH row r = RAW row r+2)
    __shared__ float HN[26*HST];    // 6656 B h11 min rows
    __shared__ float HX[26*HST];    // 6656 B h11 max rows

    const int tid = threadIdx.x;
    const int xo = tid & 63, ty = tid >> 6, y0 = ty*4;
    const int bx = blockIdx.x, by = blockIdx.y, bz = blockIdx.z;
    const int tx0 = bx*TW, ty0 = by*TH;
    const bool xe = (bx==0)||(bx==IMG/TW-1);
    const bool ye = (by==0)||(by==IMG/TH-1);
    const float* Xb = X + (size_t)bz*(IMG*IMG);

    const float W0c0=w0[0], W0c1=w0[1], B0=b0[0], B1=b0[1];
    const float W1c0=w1[0], W1c1=w1[1], W2c0=w2[0], W2c1=w2[1];
    const float W3c0=w3[0], W3c1=w3[1], W4c0=w4[0], W4c1=w4[1];
    const float W5c0=w5[0], W5c1=w5[1], W6c0=w6[0], W6c1=w6[1];

    // ---- stage RAW (NaN sentinel for OOB) ----
    if (!xe) {
        for (int t=tid; t<520; t+=256) {               // 26 rows x 20 float4
            const int r = t/20, c4 = t - r*20;
            const int gy = ty0 - 5 + r;
            float4 v;
            if (!ye || (unsigned)gy < IMG)
                v = *(const float4*)(Xb + gy*IMG + (tx0-8+4*c4));
            else { const float qn=__builtin_nanf(""); v = make_float4(qn,qn,qn,qn); }
            *(float4*)&RAW[r*RST + 4*c4] = v;
        }
    } else {
        for (int t=tid; t<26*RST; t+=256) {
            const int r = t/RST, c = t - r*RST;
            const int gy = ty0-5+r, gx = tx0-8+c;
            RAW[r*RST+c] = ((unsigned)gy<IMG && (unsigned)gx<IMG)
                           ? Xb[gy*IMG+gx] : __builtin_nanf("");
        }
    }
    __syncthreads();

    const float G0=0.10628875f, G1=0.14032194f, G2=0.16577342f, G3=0.17523179f;

    // ---- gaussH producer: 4 outputs/task, 3 b128 reads + 1 b128 write (dense) ----
    auto gh_task = [&](int r, int g) {
        const int base = (r+2)*RST + 4*g;
        const float4 A  = *(const float4*)&RAW[base+4];
        const float4 Bq = *(const float4*)&RAW[base+8];
        const float4 Cq = *(const float4*)&RAW[base+12];
        float x[12] = {A.x,A.y,A.z,A.w, Bq.x,Bq.y,Bq.z,Bq.w, Cq.x,Cq.y,Cq.z,Cq.w};
        if (xe) {
#pragma unroll
            for (int i=0;i<12;++i) x[i]=nan0(x[i]);   // centers x[4..7] in-tile: nan0 identity there
        }
        float h[4];
#pragma unroll
        for (int k=0;k<4;++k)
            h[k] = G0*(x[k+1]+x[k+7]) + G1*(x[k+2]+x[k+6]) + G2*(x[k+3]+x[k+5]) + G3*x[k+4];
        *(float4*)&GH[r*GST+4*g] = make_float4(h[0],h[1],h[2],h[3]);
    };
    gh_task(tid>>4, tid&15);                     // rows 0..15
    if (tid < 96) gh_task(16+(tid>>4), tid&15);  // rows 16..21

    // ---- pool producer: h11 min&max for 4 cols; 5 b128 reads + 2 dense b128 writes ----
    auto pl_task = [&](int r, int g) {
        const int base = r*RST + 4*g;
        const float4 q0=*(const float4*)&RAW[base];
        const float4 q1=*(const float4*)&RAW[base+4];
        const float4 q2=*(const float4*)&RAW[base+8];
        const float4 q3=*(const float4*)&RAW[base+12];
        const float4 q4=*(const float4*)&RAW[base+16];
        const float x[20] = {q0.x,q0.y,q0.z,q0.w, q1.x,q1.y,q1.z,q1.w,
                             q2.x,q2.y,q2.z,q2.w, q3.x,q3.y,q3.z,q3.w,
                             q4.x,q4.y,q4.z,q4.w};
        float mn[12], mx[12];
#pragma unroll
        for (int i=0;i<12;++i) {
            mn[i] = min3f(x[i+3],x[i+4],x[i+5]);
            mx[i] = max3f(x[i+3],x[i+4],x[i+5]);
        }
        float an[4], ax[4];
#pragma unroll
        for (int k=0;k<4;++k) {                  // 11-window = m3 at offsets 0,3,6,8
            an[k] = fminf(fminf(mn[k],mn[k+3]), fminf(mn[k+6],mn[k+8]));
            ax[k] = fmaxf(fmaxf(mx[k],mx[k+3]), fmaxf(mx[k+6],mx[k+8]));
        }
        *(float4*)&HN[r*HST+4*g] = make_float4(an[0],an[1],an[2],an[3]);
        *(float4*)&HX[r*HST+4*g] = make_float4(ax[0],ax[1],ax[2],ax[3]);
    };
    pl_task(tid>>4, tid&15);                      // rows 0..15
    if (tid < 160) pl_task(16+(tid>>4), tid&15);  // rows 16..25

    float a0[4], a1[4];

    // ---- fused identity + 3x3 cross + pool3: one 18-read set (6 rows x 3 cols) ----
    {
        const int xc = xo+8;
        float cC[6], cL[6], cR[6];
#pragma unroll
        for (int i=0;i<6;++i) {
            const int rb = (y0+4+i)*RST + xc;
            cL[i]=RAW[rb-1]; cC[i]=RAW[rb]; cR[i]=RAW[rb+1];
        }
        // pool3 from raw values (NaN ignored by v_min/v_max)
        float hm[6], hx6[6];
#pragma unroll
        for (int i=0;i<6;++i) { hm[i]=min3f(cL[i],cC[i],cR[i]); hx6[i]=max3f(cL[i],cC[i],cR[i]); }
        // identity + cross from nan0'd taps (centers cC[1..4] always valid)
        float u0=cC[0], u5=cC[5];
        float l1=cL[1],l2=cL[2],l3=cL[3],l4=cL[4];
        float r1=cR[1],r2=cR[2],r3=cR[3],r4=cR[4];
        if (ye) { u0=nan0(u0); u5=nan0(u5); }
        if (xe) { l1=nan0(l1); l2=nan0(l2); l3=nan0(l3); l4=nan0(l4);
                  r1=nan0(r1); r2=nan0(r2); r3=nan0(r3); r4=nan0(r4); }
        const float up[4]={u0,cC[1],cC[2],cC[3]};
        const float dn[4]={cC[2],cC[3],cC[4],u5};
        const float lf[4]={l1,l2,l3,l4};
        const float rt[4]={r1,r2,r3,r4};
#pragma unroll
        for (int p=0;p<4;++p) {
            const float cr = 0.25f*(up[p]+dn[p]+lf[p]+rt[p]);
            a0[p] = B0 + W0c0*cC[p+1] + W1c0*cr;
            a1[p] = B1 + W0c1*cC[p+1] + W1c1*cr;
            const float mn=min3f(hm[p],hm[p+1],hm[p+2]);
            const float mx=max3f(hx6[p],hx6[p+1],hx6[p+2]);
            a0[p]+=W3c0*mn+W5c0*mx;
            a1[p]+=W3c1*mn+W5c1*mx;
        }
    }
    __syncthreads();

    // ---- gaussV from GH (dense column b32 reads) ----
    {
        float wv[10];
#pragma unroll
        for (int i=0;i<10;++i) wv[i]=GH[(y0+i)*GST+xo];
        if (ye) {
#pragma unroll
            for (int i=0;i<10;++i) wv[i]=nan0(wv[i]);
        }
#pragma unroll
        for (int p=0;p<4;++p) {
            const float s = G0*(wv[p]+wv[p+6]) + G1*(wv[p+1]+wv[p+5])
                          + G2*(wv[p+2]+wv[p+4]) + G3*wv[p+3];
            a0[p]+=W2c0*s; a1[p]+=W2c1*s;
        }
    }

    // ---- v11 van Herk over 14 rows (dense b32 reads from both planes) ----
    {
        float hn[14], hx[14];
#pragma unroll
        for (int i=0;i<14;++i) { hn[i]=HN[(y0+i)*HST+xo]; hx[i]=HX[(y0+i)*HST+xo]; }
        float an = hn[10], ax = hx[10];
#pragma unroll
        for (int i=9;i>=4;--i) { an=fminf(an,hn[i]); ax=fmaxf(ax,hx[i]); }
        const float Sn3=fminf(an,hn[3]),  Sx3=fmaxf(ax,hx[3]);
        const float Sn2=fminf(Sn3,hn[2]), Sx2=fmaxf(Sx3,hx[2]);
        const float Sn1=fminf(Sn2,hn[1]), Sx1=fmaxf(Sx2,hx[1]);
        const float Sn0=fminf(Sn1,hn[0]), Sx0=fmaxf(Sx1,hx[0]);
        const float pn1=hn[11],            px1=hx[11];
        const float pn2=fminf(pn1,hn[12]), px2=fmaxf(px1,hx[12]);
        const float pn3=fminf(pn2,hn[13]), px3=fmaxf(px2,hx[13]);
        const float on[4]={Sn0, fminf(Sn1,pn1), fminf(Sn2,pn2), fminf(Sn3,pn3)};
        const float ox[4]={Sx0, fmaxf(Sx1,px1), fmaxf(Sx2,px2), fmaxf(Sx3,px3)};
#pragma unroll
        for (int p=0;p<4;++p) {
            a0[p]+=W4c0*on[p]+W6c0*ox[p];
            a1[p]+=W4c1*on[p]+W6c1*ox[p];
        }
    }

    float* o0p = out + ((size_t)bz*2 + 0)*(IMG*IMG) + (size_t)(ty0+y0)*IMG + tx0 + xo;
    float* o1p = o0p + (IMG*IMG);
#pragma unroll
    for (int p=0;p<4;++p) {
        o0p[(size_t)p*IMG] = a0[p];
        o1p[(size_t)p*IMG] = a1[p];
    }
}

extern "C" void kernel_launch(void* const* d_in, const int* in_sizes, int n_in,
                              void* d_out, int out_size, void* d_ws, size_t ws_size,
                              hipStream_t stream) {
    const float* X  = (const float*)d_in[0];
    const float* w0 = (const float*)d_in[1];
    const float* b0 = (const float*)d_in[2];
    const float* w1 = (const float*)d_in[3];
    const float* w2 = (const float*)d_in[4];
    const float* w3 = (const float*)d_in[5];
    const float* w4 = (const float*)d_in[6];
    const float* w5 = (const float*)d_in[7];
    const float* w6 = (const float*)d_in[8];
    float* out = (float*)d_out;

    dim3 grid(IMG/TW, IMG/TH, 32);
    simplenet_fused<<<grid, 256, 0, stream>>>(X, w0, b0, w1, w2, w3, w4, w5, w6, out);
}